// Round 2
// baseline (930.011 us; speedup 1.0000x reference)
//
#include <hip/hip_runtime.h>
#include <hip/hip_bf16.h>

#define NN 100000
#define EE 1600000
#define H  32
#define EIN 3
#define EH 32
#define EOUT 32

// ---------------------------------------------------------------------------
// Node encoder MLP: h = relu(x @ W1 + b1) @ W2 + b2      [N,2] -> [N,32]
// ---------------------------------------------------------------------------
__global__ void node_mlp_kernel(const float* __restrict__ x,
                                const float* __restrict__ w1, const float* __restrict__ b1,
                                const float* __restrict__ w2, const float* __restrict__ b2,
                                float* __restrict__ h) {
    __shared__ float sw1[2 * H];
    __shared__ float sb1[H];
    __shared__ float sw2[H * H];
    __shared__ float sb2[H];
    for (int i = threadIdx.x; i < 2 * H; i += blockDim.x) sw1[i] = w1[i];
    for (int i = threadIdx.x; i < H; i += blockDim.x) { sb1[i] = b1[i]; sb2[i] = b2[i]; }
    for (int i = threadIdx.x; i < H * H; i += blockDim.x) sw2[i] = w2[i];
    __syncthreads();

    int n = blockIdx.x * blockDim.x + threadIdx.x;
    if (n >= NN) return;

    float x0 = x[2 * n + 0];
    float x1 = x[2 * n + 1];

    float t[H];
#pragma unroll
    for (int j = 0; j < H; ++j)
        t[j] = fmaxf(fmaf(x1, sw1[H + j], fmaf(x0, sw1[j], sb1[j])), 0.0f);

    float o[H];
#pragma unroll
    for (int c = 0; c < H; ++c) o[c] = sb2[c];
#pragma unroll
    for (int j = 0; j < H; ++j) {
        float tj = t[j];
#pragma unroll
        for (int c = 0; c < H; ++c) o[c] = fmaf(tj, sw2[j * H + c], o[c]);
    }

    float4* hp = reinterpret_cast<float4*>(h + (size_t)n * H);
#pragma unroll
    for (int q = 0; q < H / 4; ++q)
        hp[q] = make_float4(o[4 * q + 0], o[4 * q + 1], o[4 * q + 2], o[4 * q + 3]);
}

// ---------------------------------------------------------------------------
// Degree / D^{-1/2}
// ---------------------------------------------------------------------------
__global__ void deg_init_kernel(float* __restrict__ dis) {
    int i = blockIdx.x * blockDim.x + threadIdx.x;
    if (i < NN) dis[i] = 1.0f;   // self-loop
}

__global__ void deg_count_kernel(const int* __restrict__ ei, float* __restrict__ dis) {
    int e = blockIdx.x * blockDim.x + threadIdx.x;
    if (e < EE) atomicAdd(&dis[ei[EE + e]], 1.0f);
}

__global__ void deg_fin_kernel(float* __restrict__ dis) {
    int i = blockIdx.x * blockDim.x + threadIdx.x;
    if (i < NN) dis[i] = 1.0f / sqrtf(dis[i]);
}

// ---------------------------------------------------------------------------
// GCN layer, stage A: hw = h @ W; acc seeded with self-loop term hw * dis^2
// ---------------------------------------------------------------------------
__global__ void gcn_hw_kernel(const float* __restrict__ h, const float* __restrict__ W,
                              const float* __restrict__ dis,
                              float* __restrict__ hw, float* __restrict__ acc) {
    __shared__ float sW[H * H];
    for (int i = threadIdx.x; i < H * H; i += blockDim.x) sW[i] = W[i];
    __syncthreads();

    int n = blockIdx.x * blockDim.x + threadIdx.x;
    if (n >= NN) return;

    float hv[H];
    const float4* hp = reinterpret_cast<const float4*>(h + (size_t)n * H);
#pragma unroll
    for (int q = 0; q < H / 4; ++q) {
        float4 v = hp[q];
        hv[4 * q + 0] = v.x; hv[4 * q + 1] = v.y; hv[4 * q + 2] = v.z; hv[4 * q + 3] = v.w;
    }

    float o[H];
#pragma unroll
    for (int c = 0; c < H; ++c) o[c] = 0.0f;
#pragma unroll
    for (int j = 0; j < H; ++j) {
        float hj = hv[j];
#pragma unroll
        for (int c = 0; c < H; ++c) o[c] = fmaf(hj, sW[j * H + c], o[c]);
    }

    float d = dis[n];
    float sl = d * d;
    float4* hwp  = reinterpret_cast<float4*>(hw  + (size_t)n * H);
    float4* accp = reinterpret_cast<float4*>(acc + (size_t)n * H);
#pragma unroll
    for (int q = 0; q < H / 4; ++q) {
        hwp[q]  = make_float4(o[4 * q + 0], o[4 * q + 1], o[4 * q + 2], o[4 * q + 3]);
        accp[q] = make_float4(o[4 * q + 0] * sl, o[4 * q + 1] * sl, o[4 * q + 2] * sl, o[4 * q + 3] * sl);
    }
}

// ---------------------------------------------------------------------------
// GCN layer, stage B: scatter  acc[dst][c] += hw[src][c]*dis[src]*dis[dst]
// one thread per (edge, channel)
// ---------------------------------------------------------------------------
__global__ void gcn_scatter_kernel(const int* __restrict__ ei, const float* __restrict__ dis,
                                   const float* __restrict__ hw, float* __restrict__ acc) {
    int i = blockIdx.x * blockDim.x + threadIdx.x;
    if (i >= EE * H) return;
    int e = i >> 5;          // /32
    int c = i & (H - 1);     // %32
    int s = ei[e];
    int d = ei[EE + e];
    float nm = dis[s] * dis[d];
    atomicAdd(&acc[(size_t)d * H + c], hw[(size_t)s * H + c] * nm);
}

// ---------------------------------------------------------------------------
// GCN layer, stage C: h = relu(acc + b)
// ---------------------------------------------------------------------------
__global__ void gcn_fin_kernel(const float* __restrict__ acc, const float* __restrict__ b,
                               float* __restrict__ h) {
    int i = blockIdx.x * blockDim.x + threadIdx.x;
    if (i < NN * H) h[i] = fmaxf(acc[i] + b[i & (H - 1)], 0.0f);
}

// ---------------------------------------------------------------------------
// Edge MLP: e = relu(concat(h[src], h[dst], ea) @ W1 + b1) @ W2 + b2
// ---------------------------------------------------------------------------
__global__ void edge_mlp_kernel(const int* __restrict__ ei, const float* __restrict__ ea,
                                const float* __restrict__ h,
                                const float* __restrict__ w1, const float* __restrict__ b1,
                                const float* __restrict__ w2, const float* __restrict__ b2,
                                float* __restrict__ out) {
    __shared__ float sw1[(2 * H + EIN) * EH];
    __shared__ float sb1[EH];
    __shared__ float sw2[EH * EOUT];
    __shared__ float sb2[EOUT];
    for (int i = threadIdx.x; i < (2 * H + EIN) * EH; i += blockDim.x) sw1[i] = w1[i];
    for (int i = threadIdx.x; i < EH; i += blockDim.x) { sb1[i] = b1[i]; sb2[i] = b2[i]; }
    for (int i = threadIdx.x; i < EH * EOUT; i += blockDim.x) sw2[i] = w2[i];
    __syncthreads();

    int e = blockIdx.x * blockDim.x + threadIdx.x;
    if (e >= EE) return;

    int s = ei[e];
    int d = ei[EE + e];

    float t[EH];
#pragma unroll
    for (int c = 0; c < EH; ++c) t[c] = sb1[c];

    // h[src] contribution (input rows 0..31)
    {
        const float4* hp = reinterpret_cast<const float4*>(h + (size_t)s * H);
#pragma unroll
        for (int q = 0; q < H / 4; ++q) {
            float4 v = hp[q];
            float vv[4] = {v.x, v.y, v.z, v.w};
#pragma unroll
            for (int r = 0; r < 4; ++r) {
                float val = vv[r];
                int idx = 4 * q + r;
#pragma unroll
                for (int c = 0; c < EH; ++c) t[c] = fmaf(val, sw1[idx * EH + c], t[c]);
            }
        }
    }
    // h[dst] contribution (input rows 32..63)
    {
        const float4* hp = reinterpret_cast<const float4*>(h + (size_t)d * H);
#pragma unroll
        for (int q = 0; q < H / 4; ++q) {
            float4 v = hp[q];
            float vv[4] = {v.x, v.y, v.z, v.w};
#pragma unroll
            for (int r = 0; r < 4; ++r) {
                float val = vv[r];
                int idx = H + 4 * q + r;
#pragma unroll
                for (int c = 0; c < EH; ++c) t[c] = fmaf(val, sw1[idx * EH + c], t[c]);
            }
        }
    }
    // edge_attr contribution (input rows 64..66)
    {
        float a0 = ea[(size_t)e * EIN + 0];
        float a1 = ea[(size_t)e * EIN + 1];
        float a2 = ea[(size_t)e * EIN + 2];
#pragma unroll
        for (int c = 0; c < EH; ++c) {
            t[c] = fmaf(a0, sw1[(2 * H + 0) * EH + c], t[c]);
            t[c] = fmaf(a1, sw1[(2 * H + 1) * EH + c], t[c]);
            t[c] = fmaf(a2, sw1[(2 * H + 2) * EH + c], t[c]);
        }
    }

    float o[EOUT];
#pragma unroll
    for (int c = 0; c < EOUT; ++c) o[c] = sb2[c];
#pragma unroll
    for (int j = 0; j < EH; ++j) {
        float r = fmaxf(t[j], 0.0f);
#pragma unroll
        for (int c = 0; c < EOUT; ++c) o[c] = fmaf(r, sw2[j * EOUT + c], o[c]);
    }

    float4* op = reinterpret_cast<float4*>(out + (size_t)e * EOUT);
#pragma unroll
    for (int q = 0; q < EOUT / 4; ++q)
        op[q] = make_float4(o[4 * q + 0], o[4 * q + 1], o[4 * q + 2], o[4 * q + 3]);
}

// ---------------------------------------------------------------------------
extern "C" void kernel_launch(void* const* d_in, const int* in_sizes, int n_in,
                              void* d_out, int out_size, void* d_ws, size_t ws_size,
                              hipStream_t stream) {
    const float* x   = (const float*)d_in[0];
    const int*   ei  = (const int*)  d_in[1];
    const float* ea  = (const float*)d_in[2];
    const float* nw1 = (const float*)d_in[3];
    const float* nb1 = (const float*)d_in[4];
    const float* nw2 = (const float*)d_in[5];
    const float* nb2 = (const float*)d_in[6];
    const float* gw1 = (const float*)d_in[7];
    const float* gb1 = (const float*)d_in[8];
    const float* gw2 = (const float*)d_in[9];
    const float* gb2 = (const float*)d_in[10];
    const float* ew1 = (const float*)d_in[11];
    const float* eb1 = (const float*)d_in[12];
    const float* ew2 = (const float*)d_in[13];
    const float* eb2 = (const float*)d_in[14];

    float* h_out = (float*)d_out;                       // [N, H]
    float* e_out = (float*)d_out + (size_t)NN * H;      // [E, EOUT]

    float* ws_f = (float*)d_ws;
    float* hw   = ws_f;                                 // [N, H]
    float* acc  = ws_f + (size_t)NN * H;                // [N, H]
    float* dis  = ws_f + (size_t)2 * NN * H;            // [N]

    const int B = 256;
    dim3 blk(B);

    node_mlp_kernel<<<(NN + B - 1) / B, blk, 0, stream>>>(x, nw1, nb1, nw2, nb2, h_out);

    deg_init_kernel<<<(NN + B - 1) / B, blk, 0, stream>>>(dis);
    deg_count_kernel<<<(EE + B - 1) / B, blk, 0, stream>>>(ei, dis);
    deg_fin_kernel<<<(NN + B - 1) / B, blk, 0, stream>>>(dis);

    for (int layer = 0; layer < 2; ++layer) {
        const float* W = layer ? gw2 : gw1;
        const float* b = layer ? gb2 : gb1;
        gcn_hw_kernel<<<(NN + B - 1) / B, blk, 0, stream>>>(h_out, W, dis, hw, acc);
        gcn_scatter_kernel<<<((EE * H) + B - 1) / B, blk, 0, stream>>>(ei, dis, hw, acc);
        gcn_fin_kernel<<<((NN * H) + B - 1) / B, blk, 0, stream>>>(acc, b, h_out);
    }

    edge_mlp_kernel<<<(EE + B - 1) / B, blk, 0, stream>>>(ei, ea, h_out, ew1, eb1, ew2, eb2, e_out);
}

// Round 3
// 886.163 us; speedup vs baseline: 1.0495x; 1.0495x over previous
//
#include <hip/hip_runtime.h>
#include <hip/hip_bf16.h>

#define NN 100000
#define EE 1600000
#define H  32
#define EIN 3
#define EH 32
#define EOUT 32

// ---------------------------------------------------------------------------
// Degree / D^{-1/2}
// ---------------------------------------------------------------------------
__global__ void deg_init_kernel(float* __restrict__ dis) {
    int i = blockIdx.x * blockDim.x + threadIdx.x;
    if (i < NN) dis[i] = 1.0f;   // self-loop
}

__global__ void deg_count_kernel(const int* __restrict__ ei, float* __restrict__ dis) {
    int e = blockIdx.x * blockDim.x + threadIdx.x;
    if (e < EE) atomicAdd(&dis[ei[EE + e]], 1.0f);
}

__global__ void deg_fin_kernel(float* __restrict__ dis) {
    int i = blockIdx.x * blockDim.x + threadIdx.x;
    if (i < NN) dis[i] = 1.0f / sqrtf(dis[i]);
}

// norm[e] = dis[src]*dis[dst]  (computed once, used by both scatter passes)
__global__ void norm_kernel(const int* __restrict__ ei, const float* __restrict__ dis,
                            float* __restrict__ norm) {
    int e = blockIdx.x * blockDim.x + threadIdx.x;
    if (e < EE) norm[e] = dis[ei[e]] * dis[ei[EE + e]];
}

// ---------------------------------------------------------------------------
// Fused: node encoder MLP -> hw1 = h_enc @ gW1 ; acc seeded with self-loop
// ---------------------------------------------------------------------------
__global__ void node_hw1_kernel(const float* __restrict__ x,
                                const float* __restrict__ w1, const float* __restrict__ b1,
                                const float* __restrict__ w2, const float* __restrict__ b2,
                                const float* __restrict__ gW, const float* __restrict__ dis,
                                float* __restrict__ hw, float* __restrict__ acc) {
    __shared__ float sw1[2 * H];
    __shared__ float sb1[H];
    __shared__ float sw2[H * H];
    __shared__ float sb2[H];
    __shared__ float sgw[H * H];
    for (int i = threadIdx.x; i < 2 * H; i += blockDim.x) sw1[i] = w1[i];
    for (int i = threadIdx.x; i < H; i += blockDim.x) { sb1[i] = b1[i]; sb2[i] = b2[i]; }
    for (int i = threadIdx.x; i < H * H; i += blockDim.x) { sw2[i] = w2[i]; sgw[i] = gW[i]; }
    __syncthreads();

    int n = blockIdx.x * blockDim.x + threadIdx.x;
    if (n >= NN) return;

    float x0 = x[2 * n + 0];
    float x1 = x[2 * n + 1];

    float t[H];
#pragma unroll
    for (int j = 0; j < H; ++j)
        t[j] = fmaxf(fmaf(x1, sw1[H + j], fmaf(x0, sw1[j], sb1[j])), 0.0f);

    float henc[H];
#pragma unroll
    for (int c = 0; c < H; ++c) henc[c] = sb2[c];
#pragma unroll
    for (int j = 0; j < H; ++j) {
        float tj = t[j];
#pragma unroll
        for (int c = 0; c < H; ++c) henc[c] = fmaf(tj, sw2[j * H + c], henc[c]);
    }

    float o[H];
#pragma unroll
    for (int c = 0; c < H; ++c) o[c] = 0.0f;
#pragma unroll
    for (int j = 0; j < H; ++j) {
        float hj = henc[j];
#pragma unroll
        for (int c = 0; c < H; ++c) o[c] = fmaf(hj, sgw[j * H + c], o[c]);
    }

    float d = dis[n];
    float sl = d * d;
    float4* hwp  = reinterpret_cast<float4*>(hw  + (size_t)n * H);
    float4* accp = reinterpret_cast<float4*>(acc + (size_t)n * H);
#pragma unroll
    for (int q = 0; q < H / 4; ++q) {
        hwp[q]  = make_float4(o[4 * q + 0], o[4 * q + 1], o[4 * q + 2], o[4 * q + 3]);
        accp[q] = make_float4(o[4 * q + 0] * sl, o[4 * q + 1] * sl, o[4 * q + 2] * sl, o[4 * q + 3] * sl);
    }
}

// ---------------------------------------------------------------------------
// Scatter: acc[dst][c] += hw[src][c] * norm[e]   (thread per (edge,channel))
// ---------------------------------------------------------------------------
__global__ void gcn_scatter_kernel(const int* __restrict__ ei, const float* __restrict__ norm,
                                   const float* __restrict__ hw, float* __restrict__ acc) {
    int i = blockIdx.x * blockDim.x + threadIdx.x;
    if (i >= EE * H) return;
    int e = i >> 5;          // /32
    int c = i & (H - 1);     // %32
    int s = ei[e];
    int d = ei[EE + e];
    float nm = norm[e];
    atomicAdd(&acc[(size_t)d * H + c], hw[(size_t)s * H + c] * nm);
}

// ---------------------------------------------------------------------------
// Fused: h1 = relu(acc + b_prev); hw2 = h1 @ gW2; acc := hw2 * dis^2
// (h1 never hits memory)
// ---------------------------------------------------------------------------
__global__ void fin_hw2_kernel(const float* __restrict__ bprev, const float* __restrict__ gW,
                               const float* __restrict__ dis,
                               float* __restrict__ hw, float* __restrict__ acc) {
    __shared__ float sgw[H * H];
    __shared__ float sb[H];
    for (int i = threadIdx.x; i < H * H; i += blockDim.x) sgw[i] = gW[i];
    for (int i = threadIdx.x; i < H; i += blockDim.x) sb[i] = bprev[i];
    __syncthreads();

    int n = blockIdx.x * blockDim.x + threadIdx.x;
    if (n >= NN) return;

    float hv[H];
    const float4* ap = reinterpret_cast<const float4*>(acc + (size_t)n * H);
#pragma unroll
    for (int q = 0; q < H / 4; ++q) {
        float4 v = ap[q];
        hv[4 * q + 0] = fmaxf(v.x + sb[4 * q + 0], 0.0f);
        hv[4 * q + 1] = fmaxf(v.y + sb[4 * q + 1], 0.0f);
        hv[4 * q + 2] = fmaxf(v.z + sb[4 * q + 2], 0.0f);
        hv[4 * q + 3] = fmaxf(v.w + sb[4 * q + 3], 0.0f);
    }

    float o[H];
#pragma unroll
    for (int c = 0; c < H; ++c) o[c] = 0.0f;
#pragma unroll
    for (int j = 0; j < H; ++j) {
        float hj = hv[j];
#pragma unroll
        for (int c = 0; c < H; ++c) o[c] = fmaf(hj, sgw[j * H + c], o[c]);
    }

    float d = dis[n];
    float sl = d * d;
    float4* hwp  = reinterpret_cast<float4*>(hw  + (size_t)n * H);
    float4* accp = reinterpret_cast<float4*>(acc + (size_t)n * H);
#pragma unroll
    for (int q = 0; q < H / 4; ++q) {
        hwp[q]  = make_float4(o[4 * q + 0], o[4 * q + 1], o[4 * q + 2], o[4 * q + 3]);
        accp[q] = make_float4(o[4 * q + 0] * sl, o[4 * q + 1] * sl, o[4 * q + 2] * sl, o[4 * q + 3] * sl);
    }
}

// ---------------------------------------------------------------------------
// Fused: h = relu(acc + gb2) -> d_out ; A = h@eW1[0:32]+eb1 ; Bv = h@eW1[32:64]
// ---------------------------------------------------------------------------
__global__ void fin_ab_kernel(const float* __restrict__ acc, const float* __restrict__ gb,
                              const float* __restrict__ ew1, const float* __restrict__ eb1,
                              float* __restrict__ hout,
                              float* __restrict__ A, float* __restrict__ Bv) {
    __shared__ float sws[H * EH];   // rows 0..31 of ew1
    __shared__ float swd[H * EH];   // rows 32..63 of ew1
    __shared__ float sgb[H];
    __shared__ float seb[EH];
    for (int i = threadIdx.x; i < H * EH; i += blockDim.x) {
        sws[i] = ew1[i];
        swd[i] = ew1[H * EH + i];
    }
    for (int i = threadIdx.x; i < H; i += blockDim.x) sgb[i] = gb[i];
    for (int i = threadIdx.x; i < EH; i += blockDim.x) seb[i] = eb1[i];
    __syncthreads();

    int n = blockIdx.x * blockDim.x + threadIdx.x;
    if (n >= NN) return;

    float hv[H];
    const float4* ap = reinterpret_cast<const float4*>(acc + (size_t)n * H);
#pragma unroll
    for (int q = 0; q < H / 4; ++q) {
        float4 v = ap[q];
        hv[4 * q + 0] = fmaxf(v.x + sgb[4 * q + 0], 0.0f);
        hv[4 * q + 1] = fmaxf(v.y + sgb[4 * q + 1], 0.0f);
        hv[4 * q + 2] = fmaxf(v.z + sgb[4 * q + 2], 0.0f);
        hv[4 * q + 3] = fmaxf(v.w + sgb[4 * q + 3], 0.0f);
    }

    float av[EH], bv[EH];
#pragma unroll
    for (int c = 0; c < EH; ++c) { av[c] = seb[c]; bv[c] = 0.0f; }
#pragma unroll
    for (int j = 0; j < H; ++j) {
        float hj = hv[j];
#pragma unroll
        for (int c = 0; c < EH; ++c) {
            av[c] = fmaf(hj, sws[j * EH + c], av[c]);
            bv[c] = fmaf(hj, swd[j * EH + c], bv[c]);
        }
    }

    float4* hp = reinterpret_cast<float4*>(hout + (size_t)n * H);
    float4* Ap = reinterpret_cast<float4*>(A    + (size_t)n * EH);
    float4* Bp = reinterpret_cast<float4*>(Bv   + (size_t)n * EH);
#pragma unroll
    for (int q = 0; q < H / 4; ++q) {
        hp[q] = make_float4(hv[4 * q + 0], hv[4 * q + 1], hv[4 * q + 2], hv[4 * q + 3]);
        Ap[q] = make_float4(av[4 * q + 0], av[4 * q + 1], av[4 * q + 2], av[4 * q + 3]);
        Bp[q] = make_float4(bv[4 * q + 0], bv[4 * q + 1], bv[4 * q + 2], bv[4 * q + 3]);
    }
}

// ---------------------------------------------------------------------------
// Edge MLP (factorized): t = A[s]+Bv[d]+ea@eW1[64:67]; relu; out = t@eW2+eb2
// ---------------------------------------------------------------------------
__global__ void edge_mlp_lite_kernel(const int* __restrict__ ei, const float* __restrict__ ea,
                                     const float* __restrict__ A, const float* __restrict__ Bv,
                                     const float* __restrict__ ew1, const float* __restrict__ eb2,
                                     const float* __restrict__ w2,
                                     float* __restrict__ out) {
    __shared__ float swe[EIN * EH];   // rows 64..66 of ew1
    __shared__ float sw2[EH * EOUT];
    __shared__ float sb2[EOUT];
    for (int i = threadIdx.x; i < EIN * EH; i += blockDim.x) swe[i] = ew1[2 * H * EH + i];
    for (int i = threadIdx.x; i < EH * EOUT; i += blockDim.x) sw2[i] = w2[i];
    for (int i = threadIdx.x; i < EOUT; i += blockDim.x) sb2[i] = eb2[i];
    __syncthreads();

    int e = blockIdx.x * blockDim.x + threadIdx.x;
    if (e >= EE) return;

    int s = ei[e];
    int d = ei[EE + e];

    float a0 = ea[(size_t)e * EIN + 0];
    float a1 = ea[(size_t)e * EIN + 1];
    float a2 = ea[(size_t)e * EIN + 2];

    const float4* Ap = reinterpret_cast<const float4*>(A  + (size_t)s * EH);
    const float4* Bp = reinterpret_cast<const float4*>(Bv + (size_t)d * EH);

    float t[EH];
#pragma unroll
    for (int q = 0; q < EH / 4; ++q) {
        float4 va = Ap[q];
        float4 vb = Bp[q];
        t[4 * q + 0] = va.x + vb.x;
        t[4 * q + 1] = va.y + vb.y;
        t[4 * q + 2] = va.z + vb.z;
        t[4 * q + 3] = va.w + vb.w;
    }
#pragma unroll
    for (int c = 0; c < EH; ++c) {
        t[c] = fmaf(a0, swe[0 * EH + c], t[c]);
        t[c] = fmaf(a1, swe[1 * EH + c], t[c]);
        t[c] = fmaf(a2, swe[2 * EH + c], t[c]);
    }

    float o[EOUT];
#pragma unroll
    for (int c = 0; c < EOUT; ++c) o[c] = sb2[c];
#pragma unroll
    for (int j = 0; j < EH; ++j) {
        float r = fmaxf(t[j], 0.0f);
#pragma unroll
        for (int c = 0; c < EOUT; ++c) o[c] = fmaf(r, sw2[j * EOUT + c], o[c]);
    }

    float4* op = reinterpret_cast<float4*>(out + (size_t)e * EOUT);
#pragma unroll
    for (int q = 0; q < EOUT / 4; ++q)
        op[q] = make_float4(o[4 * q + 0], o[4 * q + 1], o[4 * q + 2], o[4 * q + 3]);
}

// ---------------------------------------------------------------------------
extern "C" void kernel_launch(void* const* d_in, const int* in_sizes, int n_in,
                              void* d_out, int out_size, void* d_ws, size_t ws_size,
                              hipStream_t stream) {
    const float* x   = (const float*)d_in[0];
    const int*   ei  = (const int*)  d_in[1];
    const float* ea  = (const float*)d_in[2];
    const float* nw1 = (const float*)d_in[3];
    const float* nb1 = (const float*)d_in[4];
    const float* nw2 = (const float*)d_in[5];
    const float* nb2 = (const float*)d_in[6];
    const float* gw1 = (const float*)d_in[7];
    const float* gb1 = (const float*)d_in[8];
    const float* gw2 = (const float*)d_in[9];
    const float* gb2 = (const float*)d_in[10];
    const float* ew1 = (const float*)d_in[11];
    const float* eb1 = (const float*)d_in[12];
    const float* ew2 = (const float*)d_in[13];
    const float* eb2 = (const float*)d_in[14];

    float* h_out = (float*)d_out;                       // [N, H]
    float* e_out = (float*)d_out + (size_t)NN * H;      // [E, EOUT]

    float* ws_f  = (float*)d_ws;
    float* hw    = ws_f;                                 // [N, H]
    float* acc   = hw   + (size_t)NN * H;                // [N, H]
    float* A     = acc  + (size_t)NN * H;                // [N, EH]
    float* Bv    = A    + (size_t)NN * EH;               // [N, EH]
    float* norm  = Bv   + (size_t)NN * EH;               // [E]
    float* dis   = norm + (size_t)EE;                    // [N]

    const int B = 256;
    dim3 blk(B);

    deg_init_kernel<<<(NN + B - 1) / B, blk, 0, stream>>>(dis);
    deg_count_kernel<<<(EE + B - 1) / B, blk, 0, stream>>>(ei, dis);
    deg_fin_kernel<<<(NN + B - 1) / B, blk, 0, stream>>>(dis);
    norm_kernel<<<(EE + B - 1) / B, blk, 0, stream>>>(ei, dis, norm);

    // layer 1 (fused with node encoder)
    node_hw1_kernel<<<(NN + B - 1) / B, blk, 0, stream>>>(x, nw1, nb1, nw2, nb2, gw1, dis, hw, acc);
    gcn_scatter_kernel<<<((EE * H) + B - 1) / B, blk, 0, stream>>>(ei, norm, hw, acc);

    // layer 2 (fin of layer 1 fused with hw of layer 2)
    fin_hw2_kernel<<<(NN + B - 1) / B, blk, 0, stream>>>(gb1, gw2, dis, hw, acc);
    gcn_scatter_kernel<<<((EE * H) + B - 1) / B, blk, 0, stream>>>(ei, norm, hw, acc);

    // fin of layer 2 fused with edge-MLP per-node precompute
    fin_ab_kernel<<<(NN + B - 1) / B, blk, 0, stream>>>(acc, gb2, ew1, eb1, h_out, A, Bv);

    // factorized edge MLP
    edge_mlp_lite_kernel<<<(EE + B - 1) / B, blk, 0, stream>>>(ei, ea, A, Bv, ew1, eb2, ew2, e_out);
}